// Round 12
// baseline (2101.606 us; speedup 1.0000x reference)
//
#include <hip/hip_runtime.h>

// 2-layer tanh RNN, B=64 T=512 H=512, f32 in/out.
// R19 = R18 (merged layers, depth-2 self-safe tag rings, proven poll with
// backoff, fast_tanh) restructured as SPLIT PHASES: the global critical
// cycle is h1's chain ONLY (h2 never feeds h1), so each step now runs
//   poll(h1) -> sweep B1 (16 loads) -> aH MFMA -> tanh -> STORE h1
//   -> aI MFMA (Wih1 x B1, reuses validated B1 regs) -> poll(h2)
//   -> sweep B2 -> aS MFMA -> tanh -> store h2.
// The h2 phase (~1us) shadows the next step's h1 propagate window, so the
// next h1 detect typically succeeds on the first sample; B1's 16-load batch
// also halves coherent-queue serialization vs the fused 32-load sweep.
// Ring safety: h1 store depends only on B1 validation; observing U's
// h1[t-1] store => U's B1 sweep of the overwritten slot is done (U's h2
// part reuses validated B1 REGISTERS, never re-reads the h1 slot). h2 ring
// keeps R16's induction (h2 store still depends on full B2 validation).
// Polls: single-sample + s_sleep(1) (R17 lesson: poll rate has a stability
// cliff; never drop backoff). All primitives R12/R15/R16/R18-proven.
// History (us/step): R7 8.94 | R8 13.5 | R9 8.98 | R10 fail | R11 17.5 |
// R12 5.55 | R13 fail | R14 fail | R15 3.91 | R16 3.44 | R17 tripwire |
// R18 3.39.

#define HD 512
#define BATCH 64
#define SEQ 512
#define NVOCAB 25
#define OUTD 1000
#define BH (BATCH * HD)   // 32768 u16 per ring slot
#define BHQ (BH / 4)      // 8192 u64 per ring slot
#define IS64_OFF 2048
#define HDR_INTS 4096
#define GUARD_MAX (1L << 23)  // spin budget (drain storms, fail-fast on bug)

typedef unsigned short u16;
typedef unsigned int u32;
typedef unsigned long long u64;
typedef __attribute__((ext_vector_type(8))) _Float16 half8;   // 8 f16 = 16B
typedef __attribute__((ext_vector_type(4))) u32 u32x4;        // 16B
typedef __attribute__((ext_vector_type(4))) float f32x4;

union Frag16 { u32x4 x; u64 q[2]; u16 h[8]; half8 v; };

__device__ __forceinline__ u16 f2h(float f) {
    union { _Float16 h; u16 u; } c; c.h = (_Float16)f; return c.u;  // RNE
}
__device__ __forceinline__ u64 ld64a(const u64* p) {
    return __hip_atomic_load((u64*)p, __ATOMIC_RELAXED, __HIP_MEMORY_SCOPE_AGENT);
}
__device__ __forceinline__ void st64a(u64* p, u64 v) {
    __hip_atomic_store(p, v, __ATOMIC_RELAXED, __HIP_MEMORY_SCOPE_AGENT);
}
// 16B device-coherent load, computed address (R12/R15/R16-proven form).
// Non-atomic OK: each 8B half carries its own tag and self-validates.
#define LDX4(dst, addr) \
    asm volatile("global_load_dwordx4 %0, %1, off sc0" : "=v"(dst) : "v"(addr))
#define WAITV0() do { \
    asm volatile("s_waitcnt vmcnt(0)" ::: "memory"); \
    __builtin_amdgcn_sched_barrier(0); \
} while (0)

__device__ __forceinline__ u64 pack_tag(const u16 hv[4], u32 tag) {
    return ((u64)(((u32)hv[0] & 0xFFFEu) | tag))
         | ((u64)hv[1] << 16) | ((u64)hv[2] << 32) | ((u64)hv[3] << 48);
}

// fast tanh: (e^{2x}-1)/(e^{2x}+1), clamp +-9 (tanh(9)=1-2e-8; e^18 finite).
// __expf -> v_exp_f32 path, __fdividef -> rcp+mul. Err ~1e-7 << f16 ulp.
__device__ __forceinline__ float fast_tanh(float x) {
    float xc = fminf(fmaxf(x, -9.0f), 9.0f);
    float E = __expf(xc + xc);
    return __fdividef(E - 1.0f, E + 1.0f);
}

// hdr ints: is64 @ [2048] (rest unused). Rings (u64 space after hdr):
// h1[2*BHQ]: slot0 = 0 (valid h1[-1]=0, tag 0), slot1 = 1 (poison tag 1);
// h2[2*BHQ]: slot0 = 1 (poison for h2[-2] read: expect tag 1, data~0, VALID
//            as h2[-2]=0), slot1 = 1 (valid h2[-1]=0, tag 1).
__global__ void init_kernel(int* hdr, u64* h1, u64* h2, const int* x32) {
    long i = (long)blockIdx.x * 256 + threadIdx.x;
    if (i < HDR_INTS) {
        if (i == IS64_OFF) {  // probe x int width: int64 LE => odd words all 0
            int all0 = 1;
            for (int j = 0; j < 64; ++j) if (x32[2 * j + 1] != 0) all0 = 0;
            hdr[i] = all0;
        } else hdr[i] = 0;
    } else {
        long r = i - HDR_INTS;
        if (r < 2L * BHQ) h1[r] = (r < BHQ) ? 0ull : 1ull;
        else if (r < 4L * BHQ) h2[r - 2L * BHQ] = 1ull;
    }
}

__global__ __launch_bounds__(64, 1) void rnn_fused(
    const float* __restrict__ Whh0, const float* __restrict__ Wih0,
    const int* __restrict__ x,
    const float* __restrict__ bih0, const float* __restrict__ bhh0,
    const float* __restrict__ Whh1, const float* __restrict__ Wih1,
    const float* __restrict__ bih1, const float* __restrict__ bhh1,
    u64* h1ring, u64* h2ring, float* h2final, int* hdr)
{
    const int lane = threadIdx.x & 63;
    const int quad = lane >> 4;
    const int l16  = lane & 15;
    const int u    = (int)blockIdx.x >> 2;      // row-unit 0..31 (16 rows)
    const int cg   = (int)blockIdx.x & 3;       // col-group 0..3 (16 cols)
    const int rowbase = u * 16;
    const int arow = rowbase + l16;             // A row (m = lane&15)
    const int row0 = rowbase + quad * 4;        // C/D rows: quad*4 + reg
    const int col  = cg * 16 + l16;             // C/D col (batch)
    // rep packet of producer unit pg (32 row-units of my cg domain): one 8B
    // packet at col cg*16+(pg&15), u64 idx pg*4+(pg&3) (row pg*16+4*(pg&3)).
    const int pg = lane & 31;
    const size_t repoff = (size_t)(cg * 16 + (pg & 15)) * 128 + pg * 4 + (pg & 3);

    // Three weight sets, f16 frags, register-resident:
    // A[m=lane&15][k=kc*32+quad*8+j], 64 VGPRs each.
    half8 A0[16], A1[16], Aw[16];
    #pragma unroll
    for (int kc = 0; kc < 16; ++kc) {
        Frag16 t0, t1, tw;
        #pragma unroll
        for (int j = 0; j < 8; ++j) {
            const int widx = arow * HD + kc * 32 + quad * 8 + j;
            t0.h[j] = f2h(Whh0[widx]);
            t1.h[j] = f2h(Whh1[widx]);
            tw.h[j] = f2h(Wih1[widx]);
        }
        A0[kc] = t0.v; A1[kc] = t1.v; Aw[kc] = tw.v;
    }
    float bs0[4], bs1[4];
    #pragma unroll
    for (int i = 0; i < 4; ++i) {
        bs0[i] = bih0[row0 + i] + bhh0[row0 + i];
        bs1[i] = bih1[row0 + i] + bhh1[row0 + i];
    }
    const int is64 = hdr[IS64_OFF];

    long guard = 0;

    for (int t = 0; t <= SEQ; ++t) {
        // x gather + embed row prefetch (read-only, cached); issued before
        // the poll so it's in flight during the wait. tt clamps the epilogue.
        const int tt = (t < SEQ) ? t : (SEQ - 1);
        int xi = is64 ? (int)((const long long*)x)[col * SEQ + tt]
                      : x[col * SEQ + tt];
        float wx[4];
        #pragma unroll
        for (int i = 0; i < 4; ++i) wx[i] = Wih0[(row0 + i) * NVOCAB + xi];

        const int rs = t & 1;                       // read slot, both rings
        const u32 e1 = (u32)((t >> 1) & 1);         // h1[t-1] state tag
        const u32 e2 = (u32)(((t + 2) >> 1) & 1);   // h2[t-2] state tag
        const u64* sb1 = h1ring + (size_t)rs * BHQ;
        const u64* sb2 = h2ring + (size_t)rs * BHQ;
        const int ws = (t + 1) & 1;                 // write slot, both rings
        const size_t po = (size_t)col * 128 + (row0 >> 2);

        // ================= h1 phase (the recurrence-critical chain) =======
        // ---- rep poll on h1 only (all 64 lanes watch the 32 producers) ----
        {
            const u64* rep = sb1 + repoff;
            for (;;) {
                u32 bad = (((u32)ld64a(rep)) ^ e1) & 1u;
                if (__ballot(bad != 0) == 0ULL) break;
                if (++guard > GUARD_MAX) break;
                __builtin_amdgcn_s_sleep(1);
            }
        }
        // ---- B1 sweep: 16 x dwordx4, self-validating ----
        const u64* pb1 = sb1 + (size_t)col * 128 + quad * 2;
        Frag16 B1[16];
        for (;;) {
            #pragma unroll
            for (int kc = 0; kc < 16; ++kc) LDX4(B1[kc].x, pb1 + kc * 8);
            WAITV0();
            u32 bad = 0;
            #pragma unroll
            for (int kc = 0; kc < 16; ++kc)
                bad |= ((((u32)B1[kc].q[0]) ^ e1) | (((u32)B1[kc].q[1]) ^ e1)) & 1u;
            if (__ballot(bad != 0) == 0ULL) break;
            if (++guard > GUARD_MAX) break;
        }
        // ---- h1[t] = tanh(Whh0*h1[t-1] + wx): 16 MFMA, 2 chains ----
        f32x4 aH0 = {0.f, 0.f, 0.f, 0.f}, aH1 = aH0;
        #pragma unroll
        for (int kc = 0; kc < 16; kc += 2) {
            aH0 = __builtin_amdgcn_mfma_f32_16x16x32_f16(A0[kc],     B1[kc].v,     aH0, 0, 0, 0);
            aH1 = __builtin_amdgcn_mfma_f32_16x16x32_f16(A0[kc + 1], B1[kc + 1].v, aH1, 0, 0, 0);
        }
        if (t < SEQ) {
            u16 h0v[4];
            #pragma unroll
            for (int i = 0; i < 4; ++i)
                h0v[i] = f2h(fast_tanh(aH0[i] + aH1[i] + bs0[i] + wx[i]));
            st64a(h1ring + (size_t)ws * BHQ + po,
                  pack_tag(h0v, (u32)(((t + 1) >> 1) & 1)));  // ASAP: feeds
        }                                                     // next step
        // ================= h2 phase (shadows next step's propagate) =======
        // ---- aI = Wih1 * h1[t-1]: reuses the VALIDATED B1 registers ----
        f32x4 aI0 = {0.f, 0.f, 0.f, 0.f}, aI1 = aI0;
        #pragma unroll
        for (int kc = 0; kc < 16; kc += 2) {
            aI0 = __builtin_amdgcn_mfma_f32_16x16x32_f16(Aw[kc],     B1[kc].v,     aI0, 0, 0, 0);
            aI1 = __builtin_amdgcn_mfma_f32_16x16x32_f16(Aw[kc + 1], B1[kc + 1].v, aI1, 0, 0, 0);
        }
        // ---- rep poll on h2 (usually instant: data is ~1 step old) ----
        {
            const u64* rep = sb2 + repoff;
            for (;;) {
                u32 bad = (((u32)ld64a(rep)) ^ e2) & 1u;
                if (__ballot(bad != 0) == 0ULL) break;
                if (++guard > GUARD_MAX) break;
                __builtin_amdgcn_s_sleep(1);
            }
        }
        // ---- B2 sweep: 16 x dwordx4, self-validating ----
        const u64* pb2 = sb2 + (size_t)col * 128 + quad * 2;
        Frag16 B2[16];
        for (;;) {
            #pragma unroll
            for (int kc = 0; kc < 16; ++kc) LDX4(B2[kc].x, pb2 + kc * 8);
            WAITV0();
            u32 bad = 0;
            #pragma unroll
            for (int kc = 0; kc < 16; ++kc)
                bad |= ((((u32)B2[kc].q[0]) ^ e2) | (((u32)B2[kc].q[1]) ^ e2)) & 1u;
            if (__ballot(bad != 0) == 0ULL) break;
            if (++guard > GUARD_MAX) break;
        }
        // ---- h2[t-1] = tanh(Whh1*h2[t-2] + aI + b): 16 MFMA, 2 chains ----
        f32x4 aS0 = {0.f, 0.f, 0.f, 0.f}, aS1 = aS0;
        #pragma unroll
        for (int kc = 0; kc < 16; kc += 2) {
            aS0 = __builtin_amdgcn_mfma_f32_16x16x32_f16(A1[kc],     B2[kc].v,     aS0, 0, 0, 0);
            aS1 = __builtin_amdgcn_mfma_f32_16x16x32_f16(A1[kc + 1], B2[kc + 1].v, aS1, 0, 0, 0);
        }
        float h1f[4]; u16 h1v[4];
        #pragma unroll
        for (int i = 0; i < 4; ++i) {
            h1f[i] = fast_tanh(aS0[i] + aS1[i] + aI0[i] + aI1[i] + bs1[i]);
            h1v[i] = f2h(h1f[i]);
        }
        if (t < SEQ) {
            if (t >= 1)
                st64a(h2ring + (size_t)ws * BHQ + po,
                      pack_tag(h1v, (u32)(((t + 3) >> 1) & 1)));
        } else {
            *(f32x4*)(h2final + col * HD + row0) = *(f32x4*)h1f;  // h2[511], f32
        }
    }
}

__global__ __launch_bounds__(256) void out_kernel(
    const float* __restrict__ h2last, const float* __restrict__ Wout,
    const float* __restrict__ bout, float* __restrict__ out)
{
    int o = blockIdx.x * 256 + threadIdx.x;
    int b = blockIdx.y;
    if (o >= OUTD) return;
    const float* hrow = h2last + b * HD;
    const float* wrow = Wout + o * HD;
    float acc = 0.f;
    for (int k = 0; k < HD; k += 4) {
        float4 hv = *(const float4*)(hrow + k);
        float4 wv = *(const float4*)(wrow + k);
        acc += hv.x * wv.x + hv.y * wv.y + hv.z * wv.z + hv.w * wv.w;
    }
    out[b * OUTD + o] = acc + bout[o];
}

extern "C" void kernel_launch(void* const* d_in, const int* in_sizes, int n_in,
                              void* d_out, int out_size, void* d_ws, size_t ws_size,
                              hipStream_t stream) {
    const int*   x     = (const int*)d_in[0];
    const float* W_ih0 = (const float*)d_in[1];
    const float* W_hh0 = (const float*)d_in[2];
    const float* b_ih0 = (const float*)d_in[3];
    const float* b_hh0 = (const float*)d_in[4];
    const float* W_ih1 = (const float*)d_in[5];
    const float* W_hh1 = (const float*)d_in[6];
    const float* b_ih1 = (const float*)d_in[7];
    const float* b_hh1 = (const float*)d_in[8];
    const float* W_out = (const float*)d_in[9];
    const float* b_out = (const float*)d_in[10];

    // ws: hdr 16KB | h1ring 2*64KB | h2ring 2*64KB | h2final 128KB = 409600 B
    const size_t needed = (size_t)HDR_INTS * 4 + 4ULL * BHQ * 8 + (size_t)BH * 4;
    if (ws_size < needed) return;  // signature: absmax=0.149 non-NaN => ws short

    int* hdr = (int*)d_ws;
    u64* h1ring = (u64*)((char*)d_ws + (size_t)HDR_INTS * 4);
    u64* h2ring = h1ring + 2ULL * BHQ;
    float* h2final = (float*)(h2ring + 2ULL * BHQ);

    const long ninit = HDR_INTS + 4L * BHQ;  // 36864
    init_kernel<<<(int)((ninit + 255) / 256), 256, 0, stream>>>(hdr, h1ring, h2ring, x);
    rnn_fused<<<128, 64, 0, stream>>>(W_hh0, W_ih0, x, b_ih0, b_hh0,
                                      W_hh1, W_ih1, b_ih1, b_hh1,
                                      h1ring, h2ring, h2final, hdr);
    out_kernel<<<dim3(4, BATCH), 256, 0, stream>>>(h2final, W_out, b_out, (float*)d_out);
}

// Round 14
// 1813.217 us; speedup vs baseline: 1.1590x; 1.1590x over previous
//
#include <hip/hip_runtime.h>

// 2-layer tanh RNN, B=64 T=512 H=512, f32 in/out.
// R21 = R18 RESTORED VERBATIM (best stable kernel, 3.39us/step) as the
// declared floor of this design. The step cycle is sync-latency-bound:
// ~0.4us store-propagate + ~1.1us detect (rep poll, 1.5 RTT) + ~0.8us
// fused sweep (1 RTT) + ~1.0us compute/issue. All counters ~1% (latency-,
// not throughput-bound). Seven-point empirical law: rep-gated poll WITH
// s_sleep backoff is the stability mechanism, not an optimization —
// R9/R12/R15/R16/R18/R19 (rep poll) all passed; R8/R13/R17/R20 (sweep-as-
// detector or no backoff) all failed/degraded: correlated retry bursts of
// bulk coherent sweeps starve producer stores at the coherence point ->
// guard exhaustion -> validly-tagged garbage -> divergent corruption.
// Closed levers: detect acceleration (R17 pipelined poll, R20 sweep-
// detector: both tripwire); phase split (R19: +1 RTT, waves are serial);
// geometry & per-CU coherent ops (R15/R16 model fit: step ~= 1.7 +
// 0.028*ops/CU, at minimum); compute fusion (R18: 6-chain, captured).
// Design: merged layers (one wave owns rows of BOTH h1,h2 per col-group;
// one B1 sweep feeds aH and aI), depth-2 self-safe tag rings (parity in
// mantissa LSB per 8B packet; stores gated on full dual validation),
// 128 WGs x 64 thr = 1 wave/CU, f16 single-pass weights (3 sets register-
// resident), fast_tanh, fire-and-forget relaxed-atomic stores.
// History (us/step): R7 8.94 | R8 13.5 | R9 8.98 | R10 fail | R11 17.5 |
// R12 5.55 | R13 fail | R14 fail | R15 3.91 | R16 3.44 | R17 tripwire |
// R18 3.39 | R19 4.05 | R20 tripwire.

#define HD 512
#define BATCH 64
#define SEQ 512
#define NVOCAB 25
#define OUTD 1000
#define BH (BATCH * HD)   // 32768 u16 per ring slot
#define BHQ (BH / 4)      // 8192 u64 per ring slot
#define IS64_OFF 2048
#define HDR_INTS 4096
#define GUARD_MAX (1L << 23)  // spin budget (drain storms, fail-fast on bug)

typedef unsigned short u16;
typedef unsigned int u32;
typedef unsigned long long u64;
typedef __attribute__((ext_vector_type(8))) _Float16 half8;   // 8 f16 = 16B
typedef __attribute__((ext_vector_type(4))) u32 u32x4;        // 16B
typedef __attribute__((ext_vector_type(4))) float f32x4;

union Frag16 { u32x4 x; u64 q[2]; u16 h[8]; half8 v; };

__device__ __forceinline__ u16 f2h(float f) {
    union { _Float16 h; u16 u; } c; c.h = (_Float16)f; return c.u;  // RNE
}
__device__ __forceinline__ u64 ld64a(const u64* p) {
    return __hip_atomic_load((u64*)p, __ATOMIC_RELAXED, __HIP_MEMORY_SCOPE_AGENT);
}
__device__ __forceinline__ void st64a(u64* p, u64 v) {
    __hip_atomic_store(p, v, __ATOMIC_RELAXED, __HIP_MEMORY_SCOPE_AGENT);
}
// 16B device-coherent load, computed address (R12/R15/R16/R18-proven form).
// Non-atomic OK: each 8B half carries its own tag and self-validates.
#define LDX4(dst, addr) \
    asm volatile("global_load_dwordx4 %0, %1, off sc0" : "=v"(dst) : "v"(addr))
#define WAITV0() do { \
    asm volatile("s_waitcnt vmcnt(0)" ::: "memory"); \
    __builtin_amdgcn_sched_barrier(0); \
} while (0)

__device__ __forceinline__ u64 pack_tag(const u16 hv[4], u32 tag) {
    return ((u64)(((u32)hv[0] & 0xFFFEu) | tag))
         | ((u64)hv[1] << 16) | ((u64)hv[2] << 32) | ((u64)hv[3] << 48);
}

// fast tanh: (e^{2x}-1)/(e^{2x}+1), clamp +-9 (tanh(9)=1-2e-8; e^18 finite).
// __expf -> v_exp_f32 path, __fdividef -> rcp+mul. Err ~1e-7 << f16 ulp.
__device__ __forceinline__ float fast_tanh(float x) {
    float xc = fminf(fmaxf(x, -9.0f), 9.0f);
    float E = __expf(xc + xc);
    return __fdividef(E - 1.0f, E + 1.0f);
}

// hdr ints: is64 @ [2048] (rest unused). Rings (u64 space after hdr):
// h1[2*BHQ]: slot0 = 0 (valid h1[-1]=0, tag 0), slot1 = 1 (poison tag 1);
// h2[2*BHQ]: slot0 = 1 (poison for h2[-2] read: expect tag 1, data~0, VALID
//            as h2[-2]=0), slot1 = 1 (valid h2[-1]=0, tag 1).
__global__ void init_kernel(int* hdr, u64* h1, u64* h2, const int* x32) {
    long i = (long)blockIdx.x * 256 + threadIdx.x;
    if (i < HDR_INTS) {
        if (i == IS64_OFF) {  // probe x int width: int64 LE => odd words all 0
            int all0 = 1;
            for (int j = 0; j < 64; ++j) if (x32[2 * j + 1] != 0) all0 = 0;
            hdr[i] = all0;
        } else hdr[i] = 0;
    } else {
        long r = i - HDR_INTS;
        if (r < 2L * BHQ) h1[r] = (r < BHQ) ? 0ull : 1ull;
        else if (r < 4L * BHQ) h2[r - 2L * BHQ] = 1ull;
    }
}

__global__ __launch_bounds__(64, 1) void rnn_fused(
    const float* __restrict__ Whh0, const float* __restrict__ Wih0,
    const int* __restrict__ x,
    const float* __restrict__ bih0, const float* __restrict__ bhh0,
    const float* __restrict__ Whh1, const float* __restrict__ Wih1,
    const float* __restrict__ bih1, const float* __restrict__ bhh1,
    u64* h1ring, u64* h2ring, float* h2final, int* hdr)
{
    const int lane = threadIdx.x & 63;
    const int quad = lane >> 4;
    const int l16  = lane & 15;
    const int u    = (int)blockIdx.x >> 2;      // row-unit 0..31 (16 rows)
    const int cg   = (int)blockIdx.x & 3;       // col-group 0..3 (16 cols)
    const int rowbase = u * 16;
    const int arow = rowbase + l16;             // A row (m = lane&15)
    const int row0 = rowbase + quad * 4;        // C/D rows: quad*4 + reg
    const int col  = cg * 16 + l16;             // C/D col (batch)
    // rep packet of producer unit pg (32 row-units of my cg domain): one 8B
    // packet at col cg*16+(pg&15), u64 idx pg*4+(pg&3) (row pg*16+4*(pg&3)).
    const int pg = lane & 31;
    const size_t repoff = (size_t)(cg * 16 + (pg & 15)) * 128 + pg * 4 + (pg & 3);

    // Three weight sets, f16 frags, register-resident:
    // A[m=lane&15][k=kc*32+quad*8+j], 64 VGPRs each.
    half8 A0[16], A1[16], Aw[16];
    #pragma unroll
    for (int kc = 0; kc < 16; ++kc) {
        Frag16 t0, t1, tw;
        #pragma unroll
        for (int j = 0; j < 8; ++j) {
            const int widx = arow * HD + kc * 32 + quad * 8 + j;
            t0.h[j] = f2h(Whh0[widx]);
            t1.h[j] = f2h(Whh1[widx]);
            tw.h[j] = f2h(Wih1[widx]);
        }
        A0[kc] = t0.v; A1[kc] = t1.v; Aw[kc] = tw.v;
    }
    float bs0[4], bs1[4];
    #pragma unroll
    for (int i = 0; i < 4; ++i) {
        bs0[i] = bih0[row0 + i] + bhh0[row0 + i];
        bs1[i] = bih1[row0 + i] + bhh1[row0 + i];
    }
    const int is64 = hdr[IS64_OFF];

    long guard = 0;

    for (int t = 0; t <= SEQ; ++t) {
        // x gather + embed row prefetch (read-only, cached); issued before
        // the poll so it's in flight during the wait. tt clamps the epilogue.
        const int tt = (t < SEQ) ? t : (SEQ - 1);
        int xi = is64 ? (int)((const long long*)x)[col * SEQ + tt]
                      : x[col * SEQ + tt];
        float wx[4];
        #pragma unroll
        for (int i = 0; i < 4; ++i) wx[i] = Wih0[(row0 + i) * NVOCAB + xi];

        const int rs = t & 1;                       // read slot, both rings
        const u32 e1 = (u32)((t >> 1) & 1);         // h1[t-1] state tag
        const u32 e2 = (u32)(((t + 2) >> 1) & 1);   // h2[t-2] state tag
        const u64* sb1 = h1ring + (size_t)rs * BHQ;
        const u64* sb2 = h2ring + (size_t)rs * BHQ;
        // ---- rep poll (proven: single sample + s_sleep backoff).
        // Lanes 0-31 watch h1 producers, lanes 32-63 watch h2 producers.
        {
            const u64* rep = (lane < 32) ? (sb1 + repoff) : (sb2 + repoff);
            const u32 exr = (lane < 32) ? e1 : e2;
            for (;;) {
                u32 bad = (((u32)ld64a(rep)) ^ exr) & 1u;
                if (__ballot(bad != 0) == 0ULL) break;
                if (++guard > GUARD_MAX) break;
                __builtin_amdgcn_s_sleep(1);
            }
        }
        // ---- combined data sweep: 32 x dwordx4, self-validating ----
        const u64* pb1 = sb1 + (size_t)col * 128 + quad * 2;
        const u64* pb2 = sb2 + (size_t)col * 128 + quad * 2;
        Frag16 B1[16], B2[16];
        for (;;) {
            #pragma unroll
            for (int kc = 0; kc < 16; ++kc) {
                LDX4(B1[kc].x, pb1 + kc * 8);
                LDX4(B2[kc].x, pb2 + kc * 8);
            }
            WAITV0();
            u32 bad = 0;
            #pragma unroll
            for (int kc = 0; kc < 16; ++kc) {
                bad |= ((((u32)B1[kc].q[0]) ^ e1) | (((u32)B1[kc].q[1]) ^ e1)) & 1u;
                bad |= ((((u32)B2[kc].q[0]) ^ e2) | (((u32)B2[kc].q[1]) ^ e2)) & 1u;
            }
            if (__ballot(bad != 0) == 0ULL) break;
            if (++guard > GUARD_MAX) break;
        }
        // ---- FUSED compute: 48 MFMAs as 6 independent interleaved chains.
        // L0: h1[t] = tanh(Whh0*h1[t-1] + wx);  L1: h2[t-1] = tanh(Whh1*
        // h2[t-2] + Wih1*h1[t-1] + b). Unconditional; stores guarded below.
        f32x4 aH0 = {0.f, 0.f, 0.f, 0.f}, aH1 = aH0;
        f32x4 aS0 = aH0, aS1 = aH0, aI0 = aH0, aI1 = aH0;
        #pragma unroll
        for (int kc = 0; kc < 16; kc += 2) {
            aH0 = __builtin_amdgcn_mfma_f32_16x16x32_f16(A0[kc],     B1[kc].v,     aH0, 0, 0, 0);
            aS0 = __builtin_amdgcn_mfma_f32_16x16x32_f16(A1[kc],     B2[kc].v,     aS0, 0, 0, 0);
            aI0 = __builtin_amdgcn_mfma_f32_16x16x32_f16(Aw[kc],     B1[kc].v,     aI0, 0, 0, 0);
            aH1 = __builtin_amdgcn_mfma_f32_16x16x32_f16(A0[kc + 1], B1[kc + 1].v, aH1, 0, 0, 0);
            aS1 = __builtin_amdgcn_mfma_f32_16x16x32_f16(A1[kc + 1], B2[kc + 1].v, aS1, 0, 0, 0);
            aI1 = __builtin_amdgcn_mfma_f32_16x16x32_f16(Aw[kc + 1], B1[kc + 1].v, aI1, 0, 0, 0);
        }
        float h0f[4], h1f[4]; u16 h0v[4], h1v[4];
        #pragma unroll
        for (int i = 0; i < 4; ++i) {
            h0f[i] = fast_tanh(aH0[i] + aH1[i] + bs0[i] + wx[i]);
            h0v[i] = f2h(h0f[i]);
            h1f[i] = fast_tanh(aS0[i] + aS1[i] + aI0[i] + aI1[i] + bs1[i]);
            h1v[i] = f2h(h1f[i]);
        }
        const int ws = (t + 1) & 1;                 // write slot, both rings
        const size_t po = (size_t)col * 128 + (row0 >> 2);
        if (t < SEQ) {
            st64a(h1ring + (size_t)ws * BHQ + po,
                  pack_tag(h0v, (u32)(((t + 1) >> 1) & 1)));
            if (t >= 1)
                st64a(h2ring + (size_t)ws * BHQ + po,
                      pack_tag(h1v, (u32)(((t + 3) >> 1) & 1)));
        } else {
            *(f32x4*)(h2final + col * HD + row0) = *(f32x4*)h1f;  // h2[511], f32
        }
    }
}

__global__ __launch_bounds__(256) void out_kernel(
    const float* __restrict__ h2last, const float* __restrict__ Wout,
    const float* __restrict__ bout, float* __restrict__ out)
{
    int o = blockIdx.x * 256 + threadIdx.x;
    int b = blockIdx.y;
    if (o >= OUTD) return;
    const float* hrow = h2last + b * HD;
    const float* wrow = Wout + o * HD;
    float acc = 0.f;
    for (int k = 0; k < HD; k += 4) {
        float4 hv = *(const float4*)(hrow + k);
        float4 wv = *(const float4*)(wrow + k);
        acc += hv.x * wv.x + hv.y * wv.y + hv.z * wv.z + hv.w * wv.w;
    }
    out[b * OUTD + o] = acc + bout[o];
}

extern "C" void kernel_launch(void* const* d_in, const int* in_sizes, int n_in,
                              void* d_out, int out_size, void* d_ws, size_t ws_size,
                              hipStream_t stream) {
    const int*   x     = (const int*)d_in[0];
    const float* W_ih0 = (const float*)d_in[1];
    const float* W_hh0 = (const float*)d_in[2];
    const float* b_ih0 = (const float*)d_in[3];
    const float* b_hh0 = (const float*)d_in[4];
    const float* W_ih1 = (const float*)d_in[5];
    const float* W_hh1 = (const float*)d_in[6];
    const float* b_ih1 = (const float*)d_in[7];
    const float* b_hh1 = (const float*)d_in[8];
    const float* W_out = (const float*)d_in[9];
    const float* b_out = (const float*)d_in[10];

    // ws: hdr 16KB | h1ring 2*64KB | h2ring 2*64KB | h2final 128KB = 409600 B
    const size_t needed = (size_t)HDR_INTS * 4 + 4ULL * BHQ * 8 + (size_t)BH * 4;
    if (ws_size < needed) return;  // signature: absmax=0.149 non-NaN => ws short

    int* hdr = (int*)d_ws;
    u64* h1ring = (u64*)((char*)d_ws + (size_t)HDR_INTS * 4);
    u64* h2ring = h1ring + 2ULL * BHQ;
    float* h2final = (float*)(h2ring + 2ULL * BHQ);

    const long ninit = HDR_INTS + 4L * BHQ;  // 36864
    init_kernel<<<(int)((ninit + 255) / 256), 256, 0, stream>>>(hdr, h1ring, h2ring, x);
    rnn_fused<<<128, 64, 0, stream>>>(W_hh0, W_ih0, x, b_ih0, b_hh0,
                                      W_hh1, W_ih1, b_ih1, b_hh1,
                                      h1ring, h2ring, h2final, hdr);
    out_kernel<<<dim3(4, BATCH), 256, 0, stream>>>(h2final, W_out, b_out, (float*)d_out);
}